// Round 5
// baseline (303.557 us; speedup 1.0000x reference)
//
#include <hip/hip_runtime.h>
#include <hip/hip_bf16.h>

#define NROWS 4096
#define NCLS  10000
#define DIM   2048
#define ALPHA_F 10.0f
#define BETA_F  2.0f

typedef __bf16 bf16x8 __attribute__((ext_vector_type(8)));
typedef float  f32x4  __attribute__((ext_vector_type(4)));

__device__ __forceinline__ unsigned short f32_to_bf16_rne(float f) {
  unsigned int u = __float_as_uint(f);
  u += 0x7FFFu + ((u >> 16) & 1u);
  return (unsigned short)(u >> 16);
}

__global__ void cast_kernel(const float* __restrict__ src,
                            unsigned short* __restrict__ dst, int n4) {
  int stride = gridDim.x * blockDim.x;
  for (int i = blockIdx.x * blockDim.x + threadIdx.x; i < n4; i += stride) {
    float4 v = reinterpret_cast<const float4*>(src)[i];
    ushort4 o;
    o.x = f32_to_bf16_rne(v.x);
    o.y = f32_to_bf16_rne(v.y);
    o.z = f32_to_bf16_rne(v.z);
    o.w = f32_to_bf16_rne(v.w);
    reinterpret_cast<ushort4*>(dst)[i] = o;
  }
}

// fp32 dot(inputs_i, kernel[targets_i]) -> dotv[i]; one wave per row.
__global__ void gather_dot_kernel(const float* __restrict__ X, const float* __restrict__ Kn,
                                  const int* __restrict__ tgt, float* __restrict__ dotv) {
  int gtid = blockIdx.x * blockDim.x + threadIdx.x;
  int wave = gtid >> 6;
  int lane = threadIdx.x & 63;
  if (wave >= NROWS) return;
  const float* xr = X + (size_t)wave * DIM;
  const float* kr = Kn + (size_t)tgt[wave] * DIM;
  float s = 0.f;
#pragma unroll
  for (int it = 0; it < DIM / 256; ++it) {
    int k = lane * 4 + it * 256;
    float4 a = *reinterpret_cast<const float4*>(xr + k);
    float4 b = *reinterpret_cast<const float4*>(kr + k);
    s += a.x * b.x + a.y * b.y + a.z * b.z + a.w * b.w;
  }
#pragma unroll
  for (int off = 32; off > 0; off >>= 1) s += __shfl_down(s, off);
  if (lane == 0) dotv[wave] = s;
}

// ---------------------------------------------------------------------------
// 256x256 8-phase bf16 MFMA A*B^T, fused reduction epilogue (no C write).
// 512 threads = 8 waves (2M x 4N). Fragment prefetch one phase ahead; the
// schedule is UNPINNED: no manual lgkmcnt, no sched_barrier -- ds_reads are
// plain C++ loads so the compiler emits fine-grained counted lgkmcnt between
// each read and its consuming MFMA (m97 behavior), letting the MFMA cluster
// start as soon as its first fragment lands. Kept: one s_barrier per phase,
// counted vmcnt(6) gates at P3/P7 (each retires exactly one tile's 4 halves
// before the barrier that publishes them), XOR slot swizzle, setprio(1)
// around MFMA clusters. Cross-wave overwrite rule: stage@p targets a region
// whose reads were consumed (hence complete) before the p-1 barrier.
// ---------------------------------------------------------------------------

#define BAR()   asm volatile("s_barrier" ::: "memory")
#define VMC6()  asm volatile("s_waitcnt vmcnt(6)" ::: "memory")
#define VMC8()  asm volatile("s_waitcnt vmcnt(8)" ::: "memory")

#define STAGE_HALF(SH, BUF, SRC, RB, H, KT, NRW)                                \
  { _Pragma("unroll")                                                           \
    for (int iss = 0; iss < 2; ++iss) {                                         \
      int lr = (H) * 128 + iss * 64 + sRow;                                     \
      int gr = (RB) + lr; if (gr > (NRW) - 1) gr = (NRW) - 1;                   \
      const unsigned short* gp = (SRC) + (size_t)gr * DIM + (KT) * 64           \
                                 + ((sSlot ^ (lr & 7)) << 3);                   \
      unsigned short* lp = &SH[BUF][lr * 64 + sSlot * 8];                       \
      __builtin_amdgcn_global_load_lds(                                         \
          (const __attribute__((address_space(1))) void*)gp,                    \
          (__attribute__((address_space(3))) void*)lp, 16, 0, 0);               \
    } }

#define READ_A(MH, BUF)                                                         \
  { _Pragma("unroll")                                                           \
    for (int m2 = 0; m2 < 4; ++m2)                                              \
      _Pragma("unroll")                                                         \
      for (int kk = 0; kk < 2; ++kk) {                                          \
        int r = (MH) * 128 + wr * 64 + m2 * 16 + fr;                            \
        int slot = (kk * 4 + kg) ^ (fr & 7);                                    \
        af[m2][kk] = *reinterpret_cast<const bf16x8*>(&shA[BUF][r * 64 + slot * 8]); \
      } }

#define READ_B(BV, NH, BUF)                                                     \
  { _Pragma("unroll")                                                           \
    for (int n2 = 0; n2 < 2; ++n2)                                              \
      _Pragma("unroll")                                                         \
      for (int kk = 0; kk < 2; ++kk) {                                          \
        int c = (NH) * 128 + wc * 32 + n2 * 16 + fr;                            \
        int slot = (kk * 4 + kg) ^ (fr & 7);                                    \
        BV[n2][kk] = *reinterpret_cast<const bf16x8*>(&shB[BUF][c * 64 + slot * 8]); \
      } }

#define MFMA_Q(MH, NH, BV)                                                      \
  { __builtin_amdgcn_s_setprio(1);                                              \
    _Pragma("unroll")                                                           \
    for (int m2 = 0; m2 < 4; ++m2)                                              \
      _Pragma("unroll")                                                         \
      for (int n2 = 0; n2 < 2; ++n2)                                            \
        _Pragma("unroll")                                                       \
        for (int kk = 0; kk < 2; ++kk)                                          \
          acc[(MH) * 4 + m2][(NH) * 2 + n2] =                                   \
              __builtin_amdgcn_mfma_f32_16x16x32_bf16(                          \
                  af[m2][kk], BV[n2][kk], acc[(MH) * 4 + m2][(NH) * 2 + n2],    \
                  0, 0, 0);                                                     \
    __builtin_amdgcn_s_setprio(0); }

template <int EP>
__global__ __launch_bounds__(512, 2)
void gemm8_kernel(const unsigned short* __restrict__ A,
                  const unsigned short* __restrict__ B,
                  int nBrows,
                  const float* __restrict__ dotv,
                  const int* __restrict__ tgt,
                  float* __restrict__ S1, float* __restrict__ Eacc,
                  float* __restrict__ CNT, float* __restrict__ simAcc) {
  __shared__ unsigned short shA[2][256 * 64];
  __shared__ unsigned short shB[2][256 * 64];
  __shared__ float redbuf[24];

  const int tid  = threadIdx.x;
  const int lane = tid & 63;
  const int wid  = tid >> 6;
  const int wr   = wid >> 2;   // 0..1
  const int wc   = wid & 3;    // 0..3
  const int fr   = lane & 15;
  const int kg   = lane >> 4;
  const int sRow  = tid >> 3;  // 0..63
  const int sSlot = tid & 7;   // 16B slot

  // XCD-aware swizzle: contiguous column-major tile chunks per XCD.
  const int lin = blockIdx.x;
  int rowTile, colTile;
  if (EP == 0) {
    int swz = (lin & 7) * 80 + (lin >> 3);   // 640 blocks, cpx=80
    colTile = swz >> 4;                      // 5 col-panels per XCD
    rowTile = swz & 15;
  } else {
    int swz = (lin & 7) * 17 + (lin >> 3);   // 136 triangle blocks, cpx=17
    int r = 0;
    while ((r + 1) * (r + 2) / 2 <= swz) ++r;
    rowTile = r;
    colTile = swz - r * (r + 1) / 2;
  }
  const int rowBase = rowTile * 256;
  const int colBase = colTile * 256;

  f32x4 acc[8][4];
  const f32x4 zero = {0.f, 0.f, 0.f, 0.f};
#pragma unroll
  for (int m = 0; m < 8; ++m)
#pragma unroll
    for (int n = 0; n < 4; ++n) acc[m][n] = zero;

  // prologue: t0 (buf0) then t1 (buf1), 8 loads each
  STAGE_HALF(shA, 0, A, rowBase, 0, 0, NROWS);
  STAGE_HALF(shA, 0, A, rowBase, 1, 0, NROWS);
  STAGE_HALF(shB, 0, B, colBase, 0, 0, nBrows);
  STAGE_HALF(shB, 0, B, colBase, 1, 0, nBrows);
  STAGE_HALF(shA, 1, A, rowBase, 0, 1, NROWS);
  STAGE_HALF(shB, 1, B, colBase, 0, 1, nBrows);
  STAGE_HALF(shB, 1, B, colBase, 1, 1, nBrows);
  STAGE_HALF(shA, 1, A, rowBase, 1, 1, NROWS);
  VMC8();                       // t0 complete (t1's 8 loads in flight)
  BAR();                        // publish t0 to all waves

  bf16x8 af[4][2], bvA[2][2], bvB[2][2];
  // initial prefetch for P1: af0(t0), bvA(t0)
  READ_A(0, 0); READ_B(bvA, 0, 0);

#pragma unroll 1
  for (int it = 0; it < 16; ++it) {
    int t2 = 2 * it + 2; if (t2 > 31) t2 = 31;   // tail: junk re-stage, never MFMA'd
    int t3 = 2 * it + 3; if (t3 > 31) t3 = 31;
    // P1: q(0,0) t0/buf0; prefetch bvB(t0)
    MFMA_Q(0, 0, bvA);
    READ_B(bvB, 1, 0);
    BAR();
    // P2: q(0,1); prefetch af1(t0); stage A0(t2)+B0(t2)->buf0
    MFMA_Q(0, 1, bvB);
    READ_A(1, 0);
    STAGE_HALF(shA, 0, A, rowBase, 0, t2, NROWS);
    STAGE_HALF(shB, 0, B, colBase, 0, t2, nBrows);
    BAR();
    // P3: q(1,0); stage B1(t2)->buf0; gate: t1 fully staged
    MFMA_Q(1, 0, bvA);
    STAGE_HALF(shB, 0, B, colBase, 1, t2, nBrows);
    VMC6();
    BAR();
    // P4: q(1,1); prefetch af0(t1),bvA(t1) from buf1; stage A1(t2)->buf0
    MFMA_Q(1, 1, bvB);
    READ_A(0, 1); READ_B(bvA, 0, 1);
    STAGE_HALF(shA, 0, A, rowBase, 1, t2, NROWS);
    BAR();
    // P5: q(0,0) t1/buf1; prefetch bvB(t1)
    MFMA_Q(0, 0, bvA);
    READ_B(bvB, 1, 1);
    BAR();
    // P6: q(0,1); prefetch af1(t1); stage A0(t3)+B0(t3)->buf1
    MFMA_Q(0, 1, bvB);
    READ_A(1, 1);
    STAGE_HALF(shA, 1, A, rowBase, 0, t3, NROWS);
    STAGE_HALF(shB, 1, B, colBase, 0, t3, nBrows);
    BAR();
    // P7: q(1,0); stage B1(t3)->buf1; gate: t2 fully staged
    MFMA_Q(1, 0, bvA);
    STAGE_HALF(shB, 1, B, colBase, 1, t3, nBrows);
    VMC6();
    BAR();
    // P8: q(1,1); prefetch af0(t2),bvA(t2) from buf0; stage A1(t3)->buf1
    MFMA_Q(1, 1, bvB);
    READ_A(0, 0); READ_B(bvA, 0, 0);
    STAGE_HALF(shA, 1, A, rowBase, 1, t3, NROWS);
    BAR();
  }

  asm volatile("s_waitcnt vmcnt(0) lgkmcnt(0)" ::: "memory");
  __syncthreads();

  // C/D layout: col-in-frag = fr, row-in-frag = kg*4 + j (m89/m91)
  // global row = rowBase + (m>>2)*128 + wr*64 + (m&3)*16 + kg*4 + j
  // global col = colBase + (n>>1)*128 + wc*32 + (n&1)*16 + fr
  if (EP == 0) {
    float* shPhi = reinterpret_cast<float*>(&shA[0][0]);
    if (tid < 256) shPhi[tid] = dotv[rowBase + tid] - BETA_F;
    __syncthreads();
#pragma unroll
    for (int m = 0; m < 8; ++m) {
#pragma unroll
      for (int j = 0; j < 4; ++j) {
        int rl = (m >> 2) * 128 + wr * 64 + (m & 3) * 16 + kg * 4 + j;
        float ph = shPhi[rl];
        float s1 = 0.f, ee = 0.f, ct = 0.f;
#pragma unroll
        for (int n = 0; n < 4; ++n) {
          int gcol = colBase + (n >> 1) * 128 + wc * 32 + (n & 1) * 16 + fr;
          float c = acc[m][n][j];
          c = fminf(fmaxf(c, -1.f), 1.f);
          if (gcol < nBrows) {
            s1 += c;
            ee += __expf(ALPHA_F * c);
            ct += (c > ph) ? 1.f : 0.f;
          }
        }
#pragma unroll
        for (int o = 1; o < 16; o <<= 1) {
          s1 += __shfl_xor(s1, o);
          ee += __shfl_xor(ee, o);
          ct += __shfl_xor(ct, o);
        }
        if (fr == 0) {
          int grow = rowBase + rl;
          atomicAdd(&S1[grow], s1);
          atomicAdd(&Eacc[grow], ee);
          atomicAdd(&CNT[grow], ct);
        }
      }
    }
  } else {
    const float wgt = (rowTile == colTile) ? 1.f : 2.f;  // symmetry: off-diag x2
    int* shT = reinterpret_cast<int*>(&shA[0][0]);
    if (tid < 256) shT[tid] = tgt[rowBase + tid];
    else shT[tid] = tgt[colBase + (tid - 256)];
    __syncthreads();
    float ps = 0.f, als = 0.f, pc = 0.f;
#pragma unroll
    for (int m = 0; m < 8; ++m) {
#pragma unroll
      for (int j = 0; j < 4; ++j) {
        int rl = (m >> 2) * 128 + wr * 64 + (m & 3) * 16 + kg * 4 + j;
        int tr = shT[rl];
#pragma unroll
        for (int n = 0; n < 4; ++n) {
          int cl = (n >> 1) * 128 + wc * 32 + (n & 1) * 16 + fr;
          float c = acc[m][n][j];   // sim is NOT clipped in the reference
          als += c;
          if (tr == shT[256 + cl]) { ps += c; pc += 1.f; }
        }
      }
    }
#pragma unroll
    for (int o = 1; o < 64; o <<= 1) {
      ps  += __shfl_xor(ps, o);
      als += __shfl_xor(als, o);
      pc  += __shfl_xor(pc, o);
    }
    if (lane == 0) {
      redbuf[wid * 3 + 0] = ps;
      redbuf[wid * 3 + 1] = als;
      redbuf[wid * 3 + 2] = pc;
    }
    __syncthreads();
    if (tid == 0) {
      float p = 0.f, a = 0.f, c2 = 0.f;
      for (int w = 0; w < 8; ++w) {
        p += redbuf[w * 3 + 0];
        a += redbuf[w * 3 + 1];
        c2 += redbuf[w * 3 + 2];
      }
      atomicAdd(&simAcc[0], wgt * p);
      atomicAdd(&simAcc[1], wgt * a);
      atomicAdd(&simAcc[2], wgt * c2);
    }
  }
}

__global__ void finalize_kernel(const float* __restrict__ dotv, const float* __restrict__ S1,
                                const float* __restrict__ Eacc, const float* __restrict__ CNT,
                                const float* __restrict__ simAcc, float* __restrict__ out) {
  __shared__ float sh[5][256];
  int tid = threadIdx.x;
  float sum_posc = 0.f, sum_s1 = 0.f, loss_sum = 0.f, mask_cnt = 0.f, correct = 0.f;
  for (int i = tid; i < NROWS; i += 256) {
    float d = dotv[i];
    float posc = fminf(fmaxf(d, -1.f), 1.f);   // pos_cos (clipped target cos)
    float phi = d - BETA_F;
    sum_posc += posc;
    sum_s1 += S1[i];
    float e = Eacc[i] - __expf(ALPHA_F * posc);   // exclude target column
    float cexcl = CNT[i] - 1.f;                   // target always counted (margin = BETA)
    float per = -phi + __logf(e) / ALPHA_F;
    if (cexcl > 0.5f) { loss_sum += per; mask_cnt += 1.f; }
    else correct += 1.f;                          // pred == target iff no non-target col > phi
  }
  sh[0][tid] = sum_posc; sh[1][tid] = sum_s1; sh[2][tid] = loss_sum;
  sh[3][tid] = mask_cnt; sh[4][tid] = correct;
  __syncthreads();
  for (int s = 128; s > 0; s >>= 1) {
    if (tid < s)
      for (int q = 0; q < 5; ++q) sh[q][tid] += sh[q][tid + s];
    __syncthreads();
  }
  if (tid == 0) {
    float posS = sh[0][0], s1S = sh[1][0], lossS = sh[2][0], maskS = sh[3][0], corr = sh[4][0];
    out[0] = lossS / fmaxf(maskS, 1.f);
    out[1] = corr / (float)NROWS;
    out[2] = posS / (float)NROWS;
    out[3] = (s1S - posS) / ((float)NROWS * (float)(NCLS - 1));
    float pos = simAcc[0], all = simAcc[1], pcnt = simAcc[2];
    out[4] = pos / pcnt;
    out[5] = (all - pos) / ((float)NROWS * (float)NROWS - pcnt);
  }
}

extern "C" void kernel_launch(void* const* d_in, const int* in_sizes, int n_in,
                              void* d_out, int out_size, void* d_ws, size_t ws_size,
                              hipStream_t stream) {
  const float* X  = (const float*)d_in[0];   // inputs  [4096][2048] f32
  const int*   tg = (const int*)d_in[1];     // targets [4096] i32
  const float* Kn = (const float*)d_in[2];   // kernel  [10000][2048] f32
  float* out = (float*)d_out;

  char* w = (char*)d_ws;
  unsigned short* bfA = (unsigned short*)w;                 // 4096*2048 bf16
  unsigned short* bfB = bfA + (size_t)NROWS * DIM;          // 10000*2048 bf16
  float* dotv   = (float*)(w + ((size_t)NROWS * DIM + (size_t)NCLS * DIM) * 2);
  float* S1     = dotv + NROWS;
  float* Eacc   = S1 + NROWS;
  float* CNT    = Eacc + NROWS;
  float* simAcc = CNT + NROWS;

  hipMemsetAsync(S1, 0, (3 * NROWS + 4) * sizeof(float), stream);

  cast_kernel<<<2048, 256, 0, stream>>>(X, bfA, NROWS * DIM / 4);
  cast_kernel<<<2048, 256, 0, stream>>>(Kn, bfB, NCLS * DIM / 4);
  gather_dot_kernel<<<NROWS / 4, 256, 0, stream>>>(X, Kn, tg, dotv);

  // main: 40x16 tiles = 640 blocks (cols clamped+masked past 10000)
  gemm8_kernel<0><<<640, 512, 0, stream>>>(
      bfA, bfB, NCLS, dotv, nullptr, S1, Eacc, CNT, nullptr);
  // sim: lower-triangle 17*8=136 blocks, off-diag weighted x2 (symmetry)
  gemm8_kernel<1><<<136, 512, 0, stream>>>(
      bfA, bfA, NROWS, nullptr, tg, nullptr, nullptr, nullptr, simAcc);

  finalize_kernel<<<1, 256, 0, stream>>>(dotv, S1, Eacc, CNT, simAcc, out);
}

// Round 6
// 258.589 us; speedup vs baseline: 1.1739x; 1.1739x over previous
//
#include <hip/hip_runtime.h>
#include <hip/hip_bf16.h>

#define NROWS 4096
#define NCLS  10000
#define DIM   2048
#define ALPHA_F 10.0f
#define BETA_F  2.0f
#define FP8_SCALE 64.0f
#define INVQ (1.0f / (FP8_SCALE * FP8_SCALE))   // undo scale^2 on dot products

typedef float f32x4 __attribute__((ext_vector_type(4)));

__device__ __forceinline__ unsigned short f32_to_bf16_rne(float f) {
  unsigned int u = __float_as_uint(f);
  u += 0x7FFFu + ((u >> 16) & 1u);
  return (unsigned short)(u >> 16);
}

// f32 -> fp8 e4m3 (OCP), pre-scaled by FP8_SCALE. 8 elems/thread/iter.
__global__ void cast_fp8_kernel(const float* __restrict__ src,
                                uint2* __restrict__ dst, int n8) {
  int stride = gridDim.x * blockDim.x;
  for (int i = blockIdx.x * blockDim.x + threadIdx.x; i < n8; i += stride) {
    float4 a = reinterpret_cast<const float4*>(src)[2 * i];
    float4 b = reinterpret_cast<const float4*>(src)[2 * i + 1];
    unsigned int w0 = __builtin_amdgcn_cvt_pk_fp8_f32(a.x * FP8_SCALE, a.y * FP8_SCALE, 0, false);
    w0 = __builtin_amdgcn_cvt_pk_fp8_f32(a.z * FP8_SCALE, a.w * FP8_SCALE, w0, true);
    unsigned int w1 = __builtin_amdgcn_cvt_pk_fp8_f32(b.x * FP8_SCALE, b.y * FP8_SCALE, 0, false);
    w1 = __builtin_amdgcn_cvt_pk_fp8_f32(b.z * FP8_SCALE, b.w * FP8_SCALE, w1, true);
    dst[i] = make_uint2(w0, w1);
  }
}

// fp32 dot(inputs_i, kernel[targets_i]) -> dotv[i]; one wave per row. Exact path.
__global__ void gather_dot_kernel(const float* __restrict__ X, const float* __restrict__ Kn,
                                  const int* __restrict__ tgt, float* __restrict__ dotv) {
  int gtid = blockIdx.x * blockDim.x + threadIdx.x;
  int wave = gtid >> 6;
  int lane = threadIdx.x & 63;
  if (wave >= NROWS) return;
  const float* xr = X + (size_t)wave * DIM;
  const float* kr = Kn + (size_t)tgt[wave] * DIM;
  float s = 0.f;
#pragma unroll
  for (int it = 0; it < DIM / 256; ++it) {
    int k = lane * 4 + it * 256;
    float4 a = *reinterpret_cast<const float4*>(xr + k);
    float4 b = *reinterpret_cast<const float4*>(kr + k);
    s += a.x * b.x + a.y * b.y + a.z * b.z + a.w * b.w;
  }
#pragma unroll
  for (int off = 32; off > 0; off >>= 1) s += __shfl_down(s, off);
  if (lane == 0) dotv[wave] = s;
}

// ---------------------------------------------------------------------------
// 256x256 8-phase FP8 (e4m3) MFMA A*B^T, fused reduction epilogue.
// 512 threads = 8 waves (2M x 4N); per wave 128x64 out = acc[8][4] f32x4.
// BK=64 (64 B/row fp8). LDS = 2buf x (A[256][64] + B[256][64]) = 64 KiB.
// One gload_lds(16B)/thread per half-tile (8KB). Swizzle: XOR 8B-unit index
// with (row&6) -> multiples of 16B on the source (gload-safe), uniform
// 4 lanes/bank-pair on b64 reads (= minimum, conflict-free).
// vmcnt(3) at P3/P7 retires exactly one tile's 4 halves (in-order queue
// re-derived for 1-load halves). Fragment prefetch one phase ahead.
// ---------------------------------------------------------------------------

#define BAR()   asm volatile("s_barrier" ::: "memory")
#define VMC3()  asm volatile("s_waitcnt vmcnt(3)" ::: "memory")
#define VMC4()  asm volatile("s_waitcnt vmcnt(4)" ::: "memory")

#define STAGE_HALF(SH, BUF, SRC, RB, H, KT, NRW)                                \
  { int lr = (H) * 128 + sRow;                                                  \
    int gr = (RB) + lr; if (gr > (NRW) - 1) gr = (NRW) - 1;                     \
    const unsigned char* gp = (SRC) + (size_t)gr * DIM + (KT) * 64              \
                               + ((sS * 16) ^ ((lr & 6) << 3));                 \
    unsigned char* lp = &SH[BUF][lr * 64 + sS * 16];                            \
    __builtin_amdgcn_global_load_lds(                                           \
        (const __attribute__((address_space(1))) void*)gp,                      \
        (__attribute__((address_space(3))) void*)lp, 16, 0, 0); }

#define READ_A(MH, BUF)                                                         \
  { _Pragma("unroll")                                                           \
    for (int m2 = 0; m2 < 4; ++m2)                                              \
      _Pragma("unroll")                                                         \
      for (int kk = 0; kk < 2; ++kk) {                                          \
        int r = (MH) * 128 + wr * 64 + m2 * 16 + fr;                            \
        int off = (kk * 32 + kg * 8) ^ ((r & 6) << 3);                          \
        af[m2][kk] = *reinterpret_cast<const long*>(&shA[BUF][r * 64 + off]);   \
      } }

#define READ_B(BV, NH, BUF)                                                     \
  { _Pragma("unroll")                                                           \
    for (int n2 = 0; n2 < 2; ++n2)                                              \
      _Pragma("unroll")                                                         \
      for (int kk = 0; kk < 2; ++kk) {                                          \
        int c = (NH) * 128 + wc * 32 + n2 * 16 + fr;                            \
        int off = (kk * 32 + kg * 8) ^ ((c & 6) << 3);                          \
        BV[n2][kk] = *reinterpret_cast<const long*>(&shB[BUF][c * 64 + off]);   \
      } }

#define MFMA_Q(MH, NH, BV)                                                      \
  { __builtin_amdgcn_s_setprio(1);                                              \
    _Pragma("unroll")                                                           \
    for (int m2 = 0; m2 < 4; ++m2)                                              \
      _Pragma("unroll")                                                         \
      for (int n2 = 0; n2 < 2; ++n2)                                            \
        _Pragma("unroll")                                                       \
        for (int kk = 0; kk < 2; ++kk)                                          \
          acc[(MH) * 4 + m2][(NH) * 2 + n2] =                                   \
              __builtin_amdgcn_mfma_f32_16x16x32_fp8_fp8(                       \
                  af[m2][kk], BV[n2][kk], acc[(MH) * 4 + m2][(NH) * 2 + n2],    \
                  0, 0, 0);                                                     \
    __builtin_amdgcn_s_setprio(0); }

template <int EP>
__global__ __launch_bounds__(512, 1)
void gemm8_kernel(const unsigned char* __restrict__ A,
                  const unsigned char* __restrict__ B,
                  int nBrows,
                  const float* __restrict__ dotv,
                  const int* __restrict__ tgt,
                  float* __restrict__ S1, float* __restrict__ Eacc,
                  float* __restrict__ CNT, float* __restrict__ simAcc) {
  __shared__ unsigned char shA[2][256 * 64];
  __shared__ unsigned char shB[2][256 * 64];
  __shared__ float redbuf[24];

  const int tid  = threadIdx.x;
  const int lane = tid & 63;
  const int wid  = tid >> 6;
  const int wr   = wid >> 2;   // 0..1
  const int wc   = wid & 3;    // 0..3
  const int fr   = lane & 15;
  const int kg   = lane >> 4;
  const int sRow = tid >> 2;   // 0..127 (one 16B load per thread per half)
  const int sS   = tid & 3;    // 16B slot within 64B row

  // XCD-aware swizzle: contiguous column-major tile chunks per XCD.
  const int lin = blockIdx.x;
  int rowTile, colTile;
  if (EP == 0) {
    int swz = (lin & 7) * 80 + (lin >> 3);   // 640 blocks, cpx=80
    colTile = swz >> 4;                      // 5 col-panels per XCD
    rowTile = swz & 15;
  } else {
    int swz = (lin & 7) * 17 + (lin >> 3);   // 136 triangle blocks, cpx=17
    int r = 0;
    while ((r + 1) * (r + 2) / 2 <= swz) ++r;
    rowTile = r;
    colTile = swz - r * (r + 1) / 2;
  }
  const int rowBase = rowTile * 256;
  const int colBase = colTile * 256;

  f32x4 acc[8][4];
  const f32x4 zero = {0.f, 0.f, 0.f, 0.f};
#pragma unroll
  for (int m = 0; m < 8; ++m)
#pragma unroll
    for (int n = 0; n < 4; ++n) acc[m][n] = zero;

  // prologue: t0 (buf0) 4 halves, then t1 (buf1) 4 halves
  STAGE_HALF(shA, 0, A, rowBase, 0, 0, NROWS);
  STAGE_HALF(shA, 0, A, rowBase, 1, 0, NROWS);
  STAGE_HALF(shB, 0, B, colBase, 0, 0, nBrows);
  STAGE_HALF(shB, 0, B, colBase, 1, 0, nBrows);
  STAGE_HALF(shA, 1, A, rowBase, 0, 1, NROWS);
  STAGE_HALF(shB, 1, B, colBase, 0, 1, nBrows);
  STAGE_HALF(shB, 1, B, colBase, 1, 1, nBrows);
  STAGE_HALF(shA, 1, A, rowBase, 1, 1, NROWS);
  VMC4();                       // t0 complete (t1's 4 loads in flight)
  BAR();                        // publish t0 to all waves

  long af[4][2], bvA[2][2], bvB[2][2];
  // initial prefetch for P1: af0(t0), bvA(t0)
  READ_A(0, 0); READ_B(bvA, 0, 0);

#pragma unroll 1
  for (int it = 0; it < 16; ++it) {
    int t2 = 2 * it + 2; if (t2 > 31) t2 = 31;   // tail: junk re-stage, never MFMA'd
    int t3 = 2 * it + 3; if (t3 > 31) t3 = 31;
    // P1: q(0,0) t0/buf0; prefetch bvB(t0)
    MFMA_Q(0, 0, bvA);
    READ_B(bvB, 1, 0);
    BAR();
    // P2: q(0,1); prefetch af1(t0); stage A0(t2)+B0(t2)->buf0
    MFMA_Q(0, 1, bvB);
    READ_A(1, 0);
    STAGE_HALF(shA, 0, A, rowBase, 0, t2, NROWS);
    STAGE_HALF(shB, 0, B, colBase, 0, t2, nBrows);
    BAR();
    // P3: q(1,0); stage B1(t2)->buf0; gate: t1 fully staged (retire 4 oldest)
    MFMA_Q(1, 0, bvA);
    STAGE_HALF(shB, 0, B, colBase, 1, t2, nBrows);
    VMC3();
    BAR();
    // P4: q(1,1); prefetch af0(t1),bvA(t1) from buf1; stage A1(t2)->buf0
    MFMA_Q(1, 1, bvB);
    READ_A(0, 1); READ_B(bvA, 0, 1);
    STAGE_HALF(shA, 0, A, rowBase, 1, t2, NROWS);
    BAR();
    // P5: q(0,0) t1/buf1; prefetch bvB(t1)
    MFMA_Q(0, 0, bvA);
    READ_B(bvB, 1, 1);
    BAR();
    // P6: q(0,1); prefetch af1(t1); stage A0(t3)+B0(t3)->buf1
    MFMA_Q(0, 1, bvB);
    READ_A(1, 1);
    STAGE_HALF(shA, 1, A, rowBase, 0, t3, NROWS);
    STAGE_HALF(shB, 1, B, colBase, 0, t3, nBrows);
    BAR();
    // P7: q(1,0); stage B1(t3)->buf1; gate: t2 fully staged
    MFMA_Q(1, 0, bvA);
    STAGE_HALF(shB, 1, B, colBase, 1, t3, nBrows);
    VMC3();
    BAR();
    // P8: q(1,1); prefetch af0(t2),bvA(t2) from buf0; stage A1(t3)->buf1
    MFMA_Q(1, 1, bvB);
    READ_A(0, 0); READ_B(bvA, 0, 0);
    STAGE_HALF(shA, 1, A, rowBase, 1, t3, NROWS);
    BAR();
  }

  asm volatile("s_waitcnt vmcnt(0) lgkmcnt(0)" ::: "memory");
  __syncthreads();

  // C/D layout: col-in-frag = fr, row-in-frag = kg*4 + j (shape-determined)
  if (EP == 0) {
    float* shPhi = reinterpret_cast<float*>(&shA[0][0]);
    if (tid < 256) shPhi[tid] = dotv[rowBase + tid] - BETA_F;
    __syncthreads();
#pragma unroll
    for (int m = 0; m < 8; ++m) {
#pragma unroll
      for (int j = 0; j < 4; ++j) {
        int rl = (m >> 2) * 128 + wr * 64 + (m & 3) * 16 + kg * 4 + j;
        float ph = shPhi[rl];
        float s1 = 0.f, ee = 0.f, ct = 0.f;
#pragma unroll
        for (int n = 0; n < 4; ++n) {
          int gcol = colBase + (n >> 1) * 128 + wc * 32 + (n & 1) * 16 + fr;
          float c = acc[m][n][j] * INVQ;
          c = fminf(fmaxf(c, -1.f), 1.f);
          if (gcol < nBrows) {
            s1 += c;
            ee += __expf(ALPHA_F * c);
            ct += (c > ph) ? 1.f : 0.f;
          }
        }
#pragma unroll
        for (int o = 1; o < 16; o <<= 1) {
          s1 += __shfl_xor(s1, o);
          ee += __shfl_xor(ee, o);
          ct += __shfl_xor(ct, o);
        }
        if (fr == 0) {
          int grow = rowBase + rl;
          atomicAdd(&S1[grow], s1);
          atomicAdd(&Eacc[grow], ee);
          atomicAdd(&CNT[grow], ct);
        }
      }
    }
  } else {
    const float wgt = (rowTile == colTile) ? 1.f : 2.f;  // symmetry: off-diag x2
    int* shT = reinterpret_cast<int*>(&shA[0][0]);
    if (tid < 256) shT[tid] = tgt[rowBase + tid];
    else shT[tid] = tgt[colBase + (tid - 256)];
    __syncthreads();
    float ps = 0.f, als = 0.f, pc = 0.f;
#pragma unroll
    for (int m = 0; m < 8; ++m) {
#pragma unroll
      for (int j = 0; j < 4; ++j) {
        int rl = (m >> 2) * 128 + wr * 64 + (m & 3) * 16 + kg * 4 + j;
        int tr = shT[rl];
#pragma unroll
        for (int n = 0; n < 4; ++n) {
          int cl = (n >> 1) * 128 + wc * 32 + (n & 1) * 16 + fr;
          float c = acc[m][n][j] * INVQ;   // sim is NOT clipped in the reference
          als += c;
          if (tr == shT[256 + cl]) { ps += c; pc += 1.f; }
        }
      }
    }
#pragma unroll
    for (int o = 1; o < 64; o <<= 1) {
      ps  += __shfl_xor(ps, o);
      als += __shfl_xor(als, o);
      pc  += __shfl_xor(pc, o);
    }
    if (lane == 0) {
      redbuf[wid * 3 + 0] = ps;
      redbuf[wid * 3 + 1] = als;
      redbuf[wid * 3 + 2] = pc;
    }
    __syncthreads();
    if (tid == 0) {
      float p = 0.f, a = 0.f, c2 = 0.f;
      for (int w = 0; w < 8; ++w) {
        p += redbuf[w * 3 + 0];
        a += redbuf[w * 3 + 1];
        c2 += redbuf[w * 3 + 2];
      }
      atomicAdd(&simAcc[0], wgt * p);
      atomicAdd(&simAcc[1], wgt * a);
      atomicAdd(&simAcc[2], wgt * c2);
    }
  }
}

__global__ void finalize_kernel(const float* __restrict__ dotv, const float* __restrict__ S1,
                                const float* __restrict__ Eacc, const float* __restrict__ CNT,
                                const float* __restrict__ simAcc, float* __restrict__ out) {
  __shared__ float sh[5][256];
  int tid = threadIdx.x;
  float sum_posc = 0.f, sum_s1 = 0.f, loss_sum = 0.f, mask_cnt = 0.f, correct = 0.f;
  for (int i = tid; i < NROWS; i += 256) {
    float d = dotv[i];
    float posc = fminf(fmaxf(d, -1.f), 1.f);   // pos_cos (clipped target cos)
    float phi = d - BETA_F;
    sum_posc += posc;
    sum_s1 += S1[i];
    float e = Eacc[i] - __expf(ALPHA_F * posc);   // exclude target column
    float cexcl = CNT[i] - 1.f;                   // target always counted (margin = BETA)
    float per = -phi + __logf(e) / ALPHA_F;
    if (cexcl > 0.5f) { loss_sum += per; mask_cnt += 1.f; }
    else correct += 1.f;                          // pred == target iff no non-target col > phi
  }
  sh[0][tid] = sum_posc; sh[1][tid] = sum_s1; sh[2][tid] = loss_sum;
  sh[3][tid] = mask_cnt; sh[4][tid] = correct;
  __syncthreads();
  for (int s = 128; s > 0; s >>= 1) {
    if (tid < s)
      for (int q = 0; q < 5; ++q) sh[q][tid] += sh[q][tid + s];
    __syncthreads();
  }
  if (tid == 0) {
    float posS = sh[0][0], s1S = sh[1][0], lossS = sh[2][0], maskS = sh[3][0], corr = sh[4][0];
    out[0] = lossS / fmaxf(maskS, 1.f);
    out[1] = corr / (float)NROWS;
    out[2] = posS / (float)NROWS;
    out[3] = (s1S - posS) / ((float)NROWS * (float)(NCLS - 1));
    float pos = simAcc[0], all = simAcc[1], pcnt = simAcc[2];
    out[4] = pos / pcnt;
    out[5] = (all - pos) / ((float)NROWS * (float)NROWS - pcnt);
  }
}

extern "C" void kernel_launch(void* const* d_in, const int* in_sizes, int n_in,
                              void* d_out, int out_size, void* d_ws, size_t ws_size,
                              hipStream_t stream) {
  const float* X  = (const float*)d_in[0];   // inputs  [4096][2048] f32
  const int*   tg = (const int*)d_in[1];     // targets [4096] i32
  const float* Kn = (const float*)d_in[2];   // kernel  [10000][2048] f32
  float* out = (float*)d_out;

  char* w = (char*)d_ws;
  unsigned char* f8A = (unsigned char*)w;                  // 4096*2048 fp8
  unsigned char* f8B = f8A + (size_t)NROWS * DIM;          // 10000*2048 fp8
  float* dotv   = (float*)(w + (size_t)NROWS * DIM + (size_t)NCLS * DIM);
  float* S1     = dotv + NROWS;
  float* Eacc   = S1 + NROWS;
  float* CNT    = Eacc + NROWS;
  float* simAcc = CNT + NROWS;

  hipMemsetAsync(S1, 0, (3 * NROWS + 4) * sizeof(float), stream);

  cast_fp8_kernel<<<2048, 256, 0, stream>>>(X, (uint2*)f8A, NROWS * DIM / 8);
  cast_fp8_kernel<<<2048, 256, 0, stream>>>(Kn, (uint2*)f8B, NCLS * DIM / 8);
  gather_dot_kernel<<<NROWS / 4, 256, 0, stream>>>(X, Kn, tg, dotv);

  // main: 40x16 tiles = 640 blocks (cols clamped+masked past 10000)
  gemm8_kernel<0><<<640, 512, 0, stream>>>(
      f8A, f8B, NCLS, dotv, nullptr, S1, Eacc, CNT, nullptr);
  // sim: lower-triangle 17*8=136 blocks, off-diag weighted x2 (symmetry)
  gemm8_kernel<1><<<136, 512, 0, stream>>>(
      f8A, f8A, NROWS, nullptr, tg, nullptr, nullptr, nullptr, simAcc);

  finalize_kernel<<<1, 256, 0, stream>>>(dotv, S1, Eacc, CNT, simAcc, out);
}

// Round 7
// 219.867 us; speedup vs baseline: 1.3806x; 1.1761x over previous
//
#include <hip/hip_runtime.h>
#include <hip/hip_bf16.h>

#define NROWS 4096
#define NCLS  10000
#define DIM   2048
#define ALPHA_F 10.0f
#define BETA_F  2.0f
#define FP8_SCALE 64.0f
#define INVQ (1.0f / (FP8_SCALE * FP8_SCALE))   // undo scale^2 on dot products

typedef float f32x4 __attribute__((ext_vector_type(4)));
typedef int   i32x4 __attribute__((ext_vector_type(4)));
typedef int   i32x8 __attribute__((ext_vector_type(8)));

// f32 -> fp8 e4m3 (OCP), pre-scaled by FP8_SCALE. 8 elems/thread/iter.
__global__ void cast_fp8_kernel(const float* __restrict__ src,
                                uint2* __restrict__ dst, int n8) {
  int stride = gridDim.x * blockDim.x;
  for (int i = blockIdx.x * blockDim.x + threadIdx.x; i < n8; i += stride) {
    float4 a = reinterpret_cast<const float4*>(src)[2 * i];
    float4 b = reinterpret_cast<const float4*>(src)[2 * i + 1];
    unsigned int w0 = __builtin_amdgcn_cvt_pk_fp8_f32(a.x * FP8_SCALE, a.y * FP8_SCALE, 0, false);
    w0 = __builtin_amdgcn_cvt_pk_fp8_f32(a.z * FP8_SCALE, a.w * FP8_SCALE, w0, true);
    unsigned int w1 = __builtin_amdgcn_cvt_pk_fp8_f32(b.x * FP8_SCALE, b.y * FP8_SCALE, 0, false);
    w1 = __builtin_amdgcn_cvt_pk_fp8_f32(b.z * FP8_SCALE, b.w * FP8_SCALE, w1, true);
    dst[i] = make_uint2(w0, w1);
  }
}

// fp32 dot(inputs_i, kernel[targets_i]) -> dotv[i]; one wave per row. Exact path.
__global__ void gather_dot_kernel(const float* __restrict__ X, const float* __restrict__ Kn,
                                  const int* __restrict__ tgt, float* __restrict__ dotv) {
  int gtid = blockIdx.x * blockDim.x + threadIdx.x;
  int wave = gtid >> 6;
  int lane = threadIdx.x & 63;
  if (wave >= NROWS) return;
  const float* xr = X + (size_t)wave * DIM;
  const float* kr = Kn + (size_t)tgt[wave] * DIM;
  float s = 0.f;
#pragma unroll
  for (int it = 0; it < DIM / 256; ++it) {
    int k = lane * 4 + it * 256;
    float4 a = *reinterpret_cast<const float4*>(xr + k);
    float4 b = *reinterpret_cast<const float4*>(kr + k);
    s += a.x * b.x + a.y * b.y + a.z * b.z + a.w * b.w;
  }
#pragma unroll
  for (int off = 32; off > 0; off >>= 1) s += __shfl_down(s, off);
  if (lane == 0) dotv[wave] = s;
}

// ---------------------------------------------------------------------------
// 256x256 MX-fp8 (e4m3, unit scales) K=128 MFMA A*B^T, fused reduction
// epilogue (no C write). 512 threads = 8 waves (2M x 4N), per wave 128x64.
// mfma_scale_f32_16x16x128_f8f6f4: lane (fr,kg) holds 32 contiguous K-bytes
// [kg*32, kg*32+32) -> kg<2 reads the even K-tile, kg>=2 the odd K-tile.
// LDS = 4 tile-buffers x (A[256][64] + B[256][64]) = 128 KiB. Iter i reads
// buf pair {2(i&1),+1}, stages the OTHER pair (tiles 2i+2, 2i+3): reads and
// writes disjoint -> ONE s_waitcnt(0)+s_barrier per K=128 iteration, drain
// pre-aged ~2000 cyc (stages issued at iter start).
// Swizzle: 16B slot s of row r holds global slot s ^ ((r>>1)&3) (inverse
// applied on gload source); b128 frag reads -> 8 lanes/16B bank group = floor.
// ---------------------------------------------------------------------------

#define STAGE_HALF(MAT, BUF, SRC, RB, H, KT, NRW)                               \
  { int lr = (H) * 128 + sRow;                                                  \
    int gr = (RB) + lr; if (gr > (NRW) - 1) gr = (NRW) - 1;                     \
    const unsigned char* gp = (SRC) + (size_t)gr * DIM + (KT) * 64              \
                               + ((sS ^ ((lr >> 1) & 3)) << 4);                 \
    unsigned char* lp = lds + (BUF) * 32768 + (MAT) * 16384 + lr * 64 + sS * 16;\
    __builtin_amdgcn_global_load_lds(                                           \
        (const __attribute__((address_space(1))) void*)gp,                      \
        (__attribute__((address_space(3))) void*)lp, 16, 0, 0); }

#define RD_FRAG(dst, MATBASE, RC)                                               \
  { int r_ = (RC);                                                              \
    const unsigned char* p_ = (MATBASE) + r_ * 64;                              \
    int sw_ = (r_ >> 1) & 3;                                                    \
    i32x4 lo_ = *reinterpret_cast<const i32x4*>(p_ + (((kgLo2 + 0) ^ sw_) << 4));\
    i32x4 hi_ = *reinterpret_cast<const i32x4*>(p_ + (((kgLo2 + 1) ^ sw_) << 4));\
    dst[0] = lo_[0]; dst[1] = lo_[1]; dst[2] = lo_[2]; dst[3] = lo_[3];         \
    dst[4] = hi_[0]; dst[5] = hi_[1]; dst[6] = hi_[2]; dst[7] = hi_[3]; }

template <int EP>
__global__ __launch_bounds__(512, 1)
void gemm8_kernel(const unsigned char* __restrict__ A,
                  const unsigned char* __restrict__ B,
                  int nBrows,
                  const float* __restrict__ dotv,
                  const int* __restrict__ tgt,
                  float* __restrict__ S1, float* __restrict__ Eacc,
                  float* __restrict__ CNT, float* __restrict__ simAcc) {
  __shared__ unsigned char lds[4 * 32768];   // 4 tile-bufs x (A 16KB + B 16KB)

  const int tid  = threadIdx.x;
  const int lane = tid & 63;
  const int wid  = tid >> 6;
  const int wr   = wid >> 2;       // 0..1
  const int wc   = wid & 3;        // 0..3
  const int fr   = lane & 15;
  const int kg   = lane >> 4;      // K-block 0..3 within K=128
  const int kgHi = kg >> 1;        // 0: even K-tile, 1: odd K-tile
  const int kgLo2 = (kg & 1) * 2;  // starting 16B slot within the 64B row
  const int sRow = tid >> 2;       // staging: 0..127
  const int sS   = tid & 3;        // staging: 16B slot

  // XCD-aware swizzle: contiguous column-major tile chunks per XCD.
  const int lin = blockIdx.x;
  int rowTile, colTile;
  if (EP == 0) {
    int swz = (lin & 7) * 80 + (lin >> 3);   // 640 blocks, cpx=80
    colTile = swz >> 4;                      // 5 col-panels per XCD
    rowTile = swz & 15;
  } else {
    int swz = (lin & 7) * 17 + (lin >> 3);   // 136 triangle blocks, cpx=17
    int r = 0;
    while ((r + 1) * (r + 2) / 2 <= swz) ++r;
    rowTile = r;
    colTile = swz - r * (r + 1) / 2;
  }
  const int rowBase = rowTile * 256;
  const int colBase = colTile * 256;

  f32x4 acc[8][4];
  const f32x4 zero = {0.f, 0.f, 0.f, 0.f};
#pragma unroll
  for (int m = 0; m < 8; ++m)
#pragma unroll
    for (int n = 0; n < 4; ++n) acc[m][n] = zero;

  // prologue: tiles 0 -> buf0, 1 -> buf1
  STAGE_HALF(0, 0, A, rowBase, 0, 0, NROWS);
  STAGE_HALF(0, 0, A, rowBase, 1, 0, NROWS);
  STAGE_HALF(1, 0, B, colBase, 0, 0, nBrows);
  STAGE_HALF(1, 0, B, colBase, 1, 0, nBrows);
  STAGE_HALF(0, 1, A, rowBase, 0, 1, NROWS);
  STAGE_HALF(0, 1, A, rowBase, 1, 1, NROWS);
  STAGE_HALF(1, 1, B, colBase, 0, 1, nBrows);
  STAGE_HALF(1, 1, B, colBase, 1, 1, nBrows);
  asm volatile("s_waitcnt vmcnt(0)\n\ts_barrier" ::: "memory");

#pragma unroll 1
  for (int it = 0; it < 16; ++it) {
    const int cb = (it & 1) * 2;       // consume buf pair base
    const int sb = 2 - cb;             // stage buf pair base
    int t2 = 2 * it + 2; if (t2 > 31) t2 = 31;   // tail: junk re-stage
    int t3 = 2 * it + 3; if (t3 > 31) t3 = 31;

    // issue all 8 stages first: they age across the whole iteration
    STAGE_HALF(0, sb,     A, rowBase, 0, t2, NROWS);
    STAGE_HALF(0, sb,     A, rowBase, 1, t2, NROWS);
    STAGE_HALF(1, sb,     B, colBase, 0, t2, nBrows);
    STAGE_HALF(1, sb,     B, colBase, 1, t2, nBrows);
    STAGE_HALF(0, sb + 1, A, rowBase, 0, t3, NROWS);
    STAGE_HALF(0, sb + 1, A, rowBase, 1, t3, NROWS);
    STAGE_HALF(1, sb + 1, B, colBase, 0, t3, nBrows);
    STAGE_HALF(1, sb + 1, B, colBase, 1, t3, nBrows);

    const unsigned char* tbase = lds + (cb + kgHi) * 32768;
    i32x8 bfr[4];
#pragma unroll
    for (int nb = 0; nb < 4; ++nb)
      RD_FRAG(bfr[nb], tbase + 16384, (nb >> 1) * 128 + wc * 32 + (nb & 1) * 16 + fr);
#pragma unroll
    for (int MH = 0; MH < 2; ++MH) {
      i32x8 afr[4];
#pragma unroll
      for (int m2 = 0; m2 < 4; ++m2)
        RD_FRAG(afr[m2], tbase, MH * 128 + wr * 64 + m2 * 16 + fr);
      __builtin_amdgcn_s_setprio(1);
#pragma unroll
      for (int m2 = 0; m2 < 4; ++m2)
#pragma unroll
        for (int nb = 0; nb < 4; ++nb)
          acc[MH * 4 + m2][nb] = __builtin_amdgcn_mfma_scale_f32_16x16x128_f8f6f4(
              afr[m2], bfr[nb], acc[MH * 4 + m2][nb], 0, 0, 0, 127, 0, 127);
      __builtin_amdgcn_s_setprio(0);
    }
    // one gate per K=128: stages issued ~2000 cyc ago -> near-free drain
    asm volatile("s_waitcnt vmcnt(0) lgkmcnt(0)\n\ts_barrier" ::: "memory");
  }

  asm volatile("s_waitcnt vmcnt(0) lgkmcnt(0)" ::: "memory");
  __syncthreads();

  // C/D layout: col-in-frag = fr, row-in-frag = kg*4 + j (shape-determined)
  // global row = rowBase + (m>>2)*128 + wr*64 + (m&3)*16 + kg*4 + j
  // global col = colBase + (n>>1)*128 + wc*32 + (n&1)*16 + fr
  if (EP == 0) {
    float* shPhi = reinterpret_cast<float*>(lds);
    if (tid < 256) shPhi[tid] = dotv[rowBase + tid] - BETA_F;
    __syncthreads();
#pragma unroll
    for (int m = 0; m < 8; ++m) {
#pragma unroll
      for (int j = 0; j < 4; ++j) {
        int rl = (m >> 2) * 128 + wr * 64 + (m & 3) * 16 + kg * 4 + j;
        float ph = shPhi[rl];
        float s1 = 0.f, ee = 0.f, ct = 0.f;
#pragma unroll
        for (int n = 0; n < 4; ++n) {
          int gcol = colBase + (n >> 1) * 128 + wc * 32 + (n & 1) * 16 + fr;
          float c = acc[m][n][j] * INVQ;
          c = fminf(fmaxf(c, -1.f), 1.f);
          if (gcol < nBrows) {
            s1 += c;
            ee += __expf(ALPHA_F * c);
            ct += (c > ph) ? 1.f : 0.f;
          }
        }
#pragma unroll
        for (int o = 1; o < 16; o <<= 1) {
          s1 += __shfl_xor(s1, o);
          ee += __shfl_xor(ee, o);
          ct += __shfl_xor(ct, o);
        }
        if (fr == 0) {
          int grow = rowBase + rl;
          atomicAdd(&S1[grow], s1);
          atomicAdd(&Eacc[grow], ee);
          atomicAdd(&CNT[grow], ct);
        }
      }
    }
  } else {
    const float wgt = (rowTile == colTile) ? 1.f : 2.f;  // symmetry: off-diag x2
    int* shT = reinterpret_cast<int*>(lds);
    float* redbuf = reinterpret_cast<float*>(lds + 8192);
    if (tid < 256) shT[tid] = tgt[rowBase + tid];
    else shT[tid] = tgt[colBase + (tid - 256)];
    __syncthreads();
    float ps = 0.f, als = 0.f, pc = 0.f;
#pragma unroll
    for (int m = 0; m < 8; ++m) {
#pragma unroll
      for (int j = 0; j < 4; ++j) {
        int rl = (m >> 2) * 128 + wr * 64 + (m & 3) * 16 + kg * 4 + j;
        int tr = shT[rl];
#pragma unroll
        for (int n = 0; n < 4; ++n) {
          int cl = (n >> 1) * 128 + wc * 32 + (n & 1) * 16 + fr;
          float c = acc[m][n][j] * INVQ;   // sim is NOT clipped in the reference
          als += c;
          if (tr == shT[256 + cl]) { ps += c; pc += 1.f; }
        }
      }
    }
#pragma unroll
    for (int o = 1; o < 64; o <<= 1) {
      ps  += __shfl_xor(ps, o);
      als += __shfl_xor(als, o);
      pc  += __shfl_xor(pc, o);
    }
    if (lane == 0) {
      redbuf[wid * 3 + 0] = ps;
      redbuf[wid * 3 + 1] = als;
      redbuf[wid * 3 + 2] = pc;
    }
    __syncthreads();
    if (tid == 0) {
      float p = 0.f, a = 0.f, c2 = 0.f;
      for (int w = 0; w < 8; ++w) {
        p += redbuf[w * 3 + 0];
        a += redbuf[w * 3 + 1];
        c2 += redbuf[w * 3 + 2];
      }
      atomicAdd(&simAcc[0], wgt * p);
      atomicAdd(&simAcc[1], wgt * a);
      atomicAdd(&simAcc[2], wgt * c2);
    }
  }
}

__global__ void finalize_kernel(const float* __restrict__ dotv, const float* __restrict__ S1,
                                const float* __restrict__ Eacc, const float* __restrict__ CNT,
                                const float* __restrict__ simAcc, float* __restrict__ out) {
  __shared__ float sh[5][256];
  int tid = threadIdx.x;
  float sum_posc = 0.f, sum_s1 = 0.f, loss_sum = 0.f, mask_cnt = 0.f, correct = 0.f;
  for (int i = tid; i < NROWS; i += 256) {
    float d = dotv[i];
    float posc = fminf(fmaxf(d, -1.f), 1.f);   // pos_cos (clipped target cos)
    float phi = d - BETA_F;
    sum_posc += posc;
    sum_s1 += S1[i];
    float e = Eacc[i] - __expf(ALPHA_F * posc);   // exclude target column
    float cexcl = CNT[i] - 1.f;                   // target always counted (margin = BETA)
    float per = -phi + __logf(e) / ALPHA_F;
    if (cexcl > 0.5f) { loss_sum += per; mask_cnt += 1.f; }
    else correct += 1.f;                          // pred == target iff no non-target col > phi
  }
  sh[0][tid] = sum_posc; sh[1][tid] = sum_s1; sh[2][tid] = loss_sum;
  sh[3][tid] = mask_cnt; sh[4][tid] = correct;
  __syncthreads();
  for (int s = 128; s > 0; s >>= 1) {
    if (tid < s)
      for (int q = 0; q < 5; ++q) sh[q][tid] += sh[q][tid + s];
    __syncthreads();
  }
  if (tid == 0) {
    float posS = sh[0][0], s1S = sh[1][0], lossS = sh[2][0], maskS = sh[3][0], corr = sh[4][0];
    out[0] = lossS / fmaxf(maskS, 1.f);
    out[1] = corr / (float)NROWS;
    out[2] = posS / (float)NROWS;
    out[3] = (s1S - posS) / ((float)NROWS * (float)(NCLS - 1));
    float pos = simAcc[0], all = simAcc[1], pcnt = simAcc[2];
    out[4] = pos / pcnt;
    out[5] = (all - pos) / ((float)NROWS * (float)NROWS - pcnt);
  }
}

extern "C" void kernel_launch(void* const* d_in, const int* in_sizes, int n_in,
                              void* d_out, int out_size, void* d_ws, size_t ws_size,
                              hipStream_t stream) {
  const float* X  = (const float*)d_in[0];   // inputs  [4096][2048] f32
  const int*   tg = (const int*)d_in[1];     // targets [4096] i32
  const float* Kn = (const float*)d_in[2];   // kernel  [10000][2048] f32
  float* out = (float*)d_out;

  char* w = (char*)d_ws;
  unsigned char* f8A = (unsigned char*)w;                  // 4096*2048 fp8
  unsigned char* f8B = f8A + (size_t)NROWS * DIM;          // 10000*2048 fp8
  float* dotv   = (float*)(w + (size_t)NROWS * DIM + (size_t)NCLS * DIM);
  float* S1     = dotv + NROWS;
  float* Eacc   = S1 + NROWS;
  float* CNT    = Eacc + NROWS;
  float* simAcc = CNT + NROWS;

  hipMemsetAsync(S1, 0, (3 * NROWS + 4) * sizeof(float), stream);

  cast_fp8_kernel<<<2048, 256, 0, stream>>>(X, (uint2*)f8A, NROWS * DIM / 8);
  cast_fp8_kernel<<<2048, 256, 0, stream>>>(Kn, (uint2*)f8B, NCLS * DIM / 8);
  gather_dot_kernel<<<NROWS / 4, 256, 0, stream>>>(X, Kn, tg, dotv);

  // main: 40x16 tiles = 640 blocks (cols clamped+masked past 10000)
  gemm8_kernel<0><<<640, 512, 0, stream>>>(
      f8A, f8B, NCLS, dotv, nullptr, S1, Eacc, CNT, nullptr);
  // sim: lower-triangle 17*8=136 blocks, off-diag weighted x2 (symmetry)
  gemm8_kernel<1><<<136, 512, 0, stream>>>(
      f8A, f8A, NROWS, nullptr, tg, nullptr, nullptr, nullptr, simAcc);

  finalize_kernel<<<1, 256, 0, stream>>>(dotv, S1, Eacc, CNT, simAcc, out);
}